// Round 9
// baseline (384.442 us; speedup 1.0000x reference)
//
#include <hip/hip_runtime.h>

#define NN     256
#define NF     127
#define DIM    128
#define NH     8
#define DH     64
#define INNER  512
#define DEPTH  6
#define NB     512
#define ATTN_SCALE 0.125f
#define LN_EPS 1e-5f

typedef unsigned int u32;

#define FMA4(A_, S_, V_) { A_.x=fmaf(S_,(V_).x,A_.x); A_.y=fmaf(S_,(V_).y,A_.y); \
                           A_.z=fmaf(S_,(V_).z,A_.z); A_.w=fmaf(S_,(V_).w,A_.w); }

__device__ __forceinline__ float wred_sum(float v){
#pragma unroll
  for(int o=32;o;o>>=1) v += __shfl_xor(v,o);
  return v;
}
__device__ __forceinline__ float wred_max(float v){
#pragma unroll
  for(int o=32;o;o>>=1) v = fmaxf(v,__shfl_xor(v,o));
  return v;
}
__device__ __forceinline__ float2 wred_sum2(float a, float b){
#pragma unroll
  for(int o=32;o;o>>=1){ a += __shfl_xor(a,o); b += __shfl_xor(b,o); }
  return make_float2(a,b);
}

// In-wave LayerNorm of a 128-dim row held as (n0,n1) = dims (l, l+64) per lane.
__device__ __forceinline__ void ln_wave(float n0, float n1,
                                        const float* g, const float* b, int l,
                                        float& x0, float& x1){
  float2 sv = wred_sum2(n0+n1, n0*n0+n1*n1);
  float m  = sv.x*(1.f/DIM);
  float var = sv.y*(1.f/DIM) - m*m;
  float rs = rsqrtf(var + LN_EPS);
  x0 = (n0-m)*rs*g[l]    + b[l];
  x1 = (n1-m)*rs*g[64+l] + b[64+l];
}

// In-wave gated residual. No barriers.
__device__ __forceinline__ void gate_wave(float o0, float o1, float& n0, float& n1,
                                          const float* Wg, int l){
  float gv = o0*Wg[l]    + n0*Wg[DIM+l]    + (o0-n0)*Wg[2*DIM+l]
           + o1*Wg[64+l] + n1*Wg[DIM+64+l] + (o1-n1)*Wg[2*DIM+64+l];
  gv = wred_sum(gv);
  float gate = 1.f/(1.f + expf(-gv));
  n0 = o0*gate + n0*(1.f-gate);
  n1 = o1*gate + n1*(1.f-gate);
}

// ---- async global->LDS staging (no VGPR round-trip, deep DMA queue) ----
__device__ __forceinline__ void gld16(const float* g, float* l){
  __builtin_amdgcn_global_load_lds(
      (const __attribute__((address_space(1))) u32*)g,
      (__attribute__((address_space(3))) u32*)l,
      16, 0, 0);
}
// stage 32KB (8192 floats) of W into stg; 512 thr: wave w issues 4x 1KB segments
__device__ __forceinline__ void stage32k(const float* __restrict__ g,
                                         float* stg, int t){
  const int w = t>>6, l = t&63;
#pragma unroll
  for(int r=0;r<4;r++){
    const int q = (r<<3) + w;               // 32 segments of 256 floats
    gld16(g + q*256 + (l<<2), stg + q*256); // lds dest wave-uniform; HW adds lane*16B
  }
}

// ---- staged matvec: x[K] (LDS) @ W[K][NCOLS] -> SC partials ----
// Chunk = 8192 floats (32KB), double-buffered in stg[16384].
// Thread t: cols cg..cg+3 (cg=(t%GROUPS)*4), row-slot s=t/GROUPS; 4 rows/chunk.
// Partials: SC[s*NCOLS + cg..], s in [0, 512/GROUPS). SC = 2048 floats always.
// Ends with SC ready (final barrier inside).
template<int NCOLS, int NCHUNK>
__device__ __forceinline__ void mv_staged(const float* __restrict__ xin,
                                          const float* __restrict__ W,
                                          float* __restrict__ stg,
                                          float* __restrict__ SC, int t){
  constexpr int GROUPS = NCOLS/4;
  constexpr int RPC    = 8192/NCOLS;        // rows per chunk
  const int cg = (t & (GROUPS-1))<<2;
  const int s  = t / GROUPS;
  const int r0 = s<<2;
  float4 acc = make_float4(0.f,0.f,0.f,0.f);
  stage32k(W, stg, t);                      // chunk 0 -> buf 0
#pragma unroll
  for(int c=0; c<NCHUNK; c++){
    __syncthreads();                        // chunk c DMA drained; old buf free
    if(c+1<NCHUNK) stage32k(W + (size_t)(c+1)*8192, stg + ((c+1)&1)*8192, t);
    const float* ch = stg + (c&1)*8192;
#pragma unroll
    for(int k=0;k<4;k++){
      float x = xin[c*RPC + r0 + k];
      float4 wv = *(const float4*)(ch + (r0+k)*NCOLS + cg);
      FMA4(acc, x, wv);
    }
  }
  *(float4*)(SC + s*NCOLS + cg) = acc;
  __syncthreads();                          // SC ready
}

// LN1 output xs[128] (LDS) -> q/k/v for row i (staged Wq then Wkv).
__device__ __forceinline__ void qkv_tail(const float* __restrict__ xs, int i,
    const float* __restrict__ Wq, const float* __restrict__ bq,
    const float* __restrict__ Wkv, const float* __restrict__ bkv,
    const float* __restrict__ be, float* qgn, float* kTn, float* vgn,
    float* __restrict__ stg, float* __restrict__ SC, int t){
  mv_staged<512,8>(xs, Wq, stg, SC, t);
  qgn[i*INNER + t] = bq[t] + SC[t] + SC[INNER+t] + SC[2*INNER+t] + SC[3*INNER+t];
  // (mv_staged's internal barriers order this read vs SC overwrite below)
  mv_staged<1024,16>(xs, Wkv, stg, SC, t);
#pragma unroll
  for(int cc=0; cc<2; cc++){
    int c = t + cc*512;
    float sv = bkv[c] + SC[c] + SC[1024 + c];
    if(c < INNER) kTn[c*NN + i]            = sv + be[c];
    else          vgn[i*INNER + c - INNER] = sv + be[c-INNER];
  }
}

// ---- layer 0: node-init + LN1 (in-wave) + QKV ----
__global__ __launch_bounds__(512) void k_qkv0(const float* atom_emb, const float* noise,
    float* nodes, const float* ln1_g, const float* ln1_b,
    const float* Wq, const float* bq, const float* Wkv, const float* bkv, const float* be,
    float* qg, float* kT, float* vg){
  __shared__ __align__(16) float stg[16384];   // 64KB staging
  __shared__ __align__(16) float SC[2048];
  __shared__ __align__(16) float xsm[DIM];
  const int t = threadIdx.x, i = blockIdx.x;
  const int w = t>>6, l = t&63;
  float nd0 = (l<NF)?    atom_emb[i*NF + l]      : noise[0];
  float nd1 = (64+l<NF)? atom_emb[i*NF + 64 + l] : noise[0];
  if(w==0){ nodes[i*DIM + l] = nd0; nodes[i*DIM + 64 + l] = nd1; }
  float x0, x1;
  ln_wave(nd0, nd1, ln1_g, ln1_b, l, x0, x1);
  xsm[l] = x0; xsm[64+l] = x1;     // all waves write identical values (benign)
  __syncthreads();
  qkv_tail(xsm, i, Wq, bq, Wkv, bkv, be, qg, kT, vg, stg, SC, t);
}

// ---- attention kernel: block = (head h, 8-row tile); wave w = row i0+w ----
__global__ __launch_bounds__(512) void k_attn(
    const float* __restrict__ qg, const float* __restrict__ kT,
    const float* __restrict__ vg,
    const int* __restrict__ bonds, const float* __restrict__ coords,
    const float* __restrict__ We, float* __restrict__ aog)
{
  __shared__ __align__(16) float qsm[8*DH];     // q head-slice, 8 rows
  __shared__ __align__(16) float eb[8][3*NN];   // per-row edge planes [x|y|z]
  __shared__ __align__(16) float aW[8][NN];     // attn weights per row
  const int t = threadIdx.x;
  const int h = blockIdx.x >> 5, i0 = (blockIdx.x & 31) << 3;
  const int w = t>>6, l = t&63;
  const int qb = h*DH, j0 = l<<2;

  qsm[w*DH + l] = qg[(i0+w)*INNER + qb + l];
#pragma unroll
  for(int cc=0; cc<12; cc++) (&eb[0][0])[cc*512 + t] = 0.f;   // 8*768 = 6144
  __syncthreads();

  // bond scatter for rows i0..i0+7 (duplicates carry identical values)
  {
    const int bi = bonds[2*t], bj = bonds[2*t+1];
    const bool hi = (bi>=i0 && bi<i0+8), hj = (bj>=i0 && bj<i0+8);
    if(hi || hj){
      float dx = coords[3*bi+0] - coords[3*bj+0];
      float dy = coords[3*bi+1] - coords[3*bj+1];
      float dz = coords[3*bi+2] - coords[3*bj+2];
      if(hi){ float* e = eb[bi-i0]; e[bj]=dx;  e[NN+bj]=dy;  e[2*NN+bj]=dz;  }
      if(hj){ float* e = eb[bj-i0]; e[bi]=-dx; e[NN+bi]=-dy; e[2*NN+bi]=-dz; }
    }
  }
  __syncthreads();

  // qwe_c = q_row . We[c, h-slice]  (in-wave butterfly)
  float qwe0, qwe1, qwe2;
  {
    float qv = qsm[w*DH + l];
    qwe0 = qv*We[0*INNER + qb + l];
    qwe1 = qv*We[1*INNER + qb + l];
    qwe2 = qv*We[2*INNER + qb + l];
#pragma unroll
    for(int o=32;o;o>>=1){
      qwe0 += __shfl_xor(qwe0,o); qwe1 += __shfl_xor(qwe1,o); qwe2 += __shfl_xor(qwe2,o);
    }
  }
  // QK^T: dual-stream over o-halves; lane l -> scores j0..j0+3 for row i0+w
  const float* __restrict__ kTh = kT + qb*NN + j0;
  float s0=0.f,s1=0.f,s2=0.f,s3=0.f;
  float u0=0.f,u1=0.f,u2=0.f,u3=0.f;
#pragma unroll
  for(int o=0;o<32;o++){
    float4 ka = *(const float4*)(kTh + o*NN);
    float4 kb = *(const float4*)(kTh + (32+o)*NN);
    float qa = qsm[w*DH + o], qc = qsm[w*DH + 32 + o];
    s0=fmaf(qa,ka.x,s0); s1=fmaf(qa,ka.y,s1); s2=fmaf(qa,ka.z,s2); s3=fmaf(qa,ka.w,s3);
    u0=fmaf(qc,kb.x,u0); u1=fmaf(qc,kb.y,u1); u2=fmaf(qc,kb.z,u2); u3=fmaf(qc,kb.w,u3);
  }
  s0+=u0; s1+=u1; s2+=u2; s3+=u3;
  const float* e = eb[w];
  float4 ex = *(const float4*)(e + j0);
  float4 ey = *(const float4*)(e + NN + j0);
  float4 ez = *(const float4*)(e + 2*NN + j0);
  s0 = (s0 + qwe0*ex.x + qwe1*ey.x + qwe2*ez.x)*ATTN_SCALE;
  s1 = (s1 + qwe0*ex.y + qwe1*ey.y + qwe2*ez.y)*ATTN_SCALE;
  s2 = (s2 + qwe0*ex.z + qwe1*ey.z + qwe2*ez.z)*ATTN_SCALE;
  s3 = (s3 + qwe0*ex.w + qwe1*ey.w + qwe2*ez.w)*ATTN_SCALE;
  float mx = wred_max(fmaxf(fmaxf(s0,s1),fmaxf(s2,s3)));
  float p0=expf(s0-mx), p1=expf(s1-mx), p2=expf(s2-mx), p3=expf(s3-mx);
  float inv = 1.f / wred_sum(p0+p1+p2+p3);
  float a0=p0*inv, a1=p1*inv, a2=p2*inv, a3=p3*inv;
  *(float4*)(aW[w] + j0) = make_float4(a0,a1,a2,a3);
  // edge moments c_c = sum_j a_j * eb[c][j]
  float c0 = a0*ex.x + a1*ex.y + a2*ex.z + a3*ex.w;
  float c1 = a0*ey.x + a1*ey.y + a2*ey.z + a3*ey.w;
  float c2 = a0*ez.x + a1*ez.y + a2*ez.z + a3*ez.w;
  c0 = wred_sum(c0); c1 = wred_sum(c1); c2 = wred_sum(c2);
  __builtin_amdgcn_wave_barrier();   // order aW writes before same-wave aW reads
  // PV: dual-stream over j-halves; lane l -> dims dq..dq+3
  const int dq = (l&15)<<2, jg = l>>4;
  const float* __restrict__ vb = vg + qb + dq;
  const float* aWw = aW[w];
  float4 acc = make_float4(0.f,0.f,0.f,0.f), acc2 = acc;
#pragma unroll
  for(int jj=0;jj<32;jj++){
    int ja = (jg<<6) + jj, jb = ja + 32;
    float4 va = *(const float4*)(vb + ja*INNER);
    float4 vv = *(const float4*)(vb + jb*INNER);
    FMA4(acc,  aWw[ja], va);
    FMA4(acc2, aWw[jb], vv);
  }
  acc.x+=acc2.x; acc.y+=acc2.y; acc.z+=acc2.z; acc.w+=acc2.w;
#pragma unroll
  for(int o=16;o<64;o<<=1){
    acc.x += __shfl_xor(acc.x,o); acc.y += __shfl_xor(acc.y,o);
    acc.z += __shfl_xor(acc.z,o); acc.w += __shfl_xor(acc.w,o);
  }
  if(l<16){
    float4 we0 = *(const float4*)(We + 0*INNER + qb + dq);
    float4 we1 = *(const float4*)(We + 1*INNER + qb + dq);
    float4 we2 = *(const float4*)(We + 2*INNER + qb + dq);
    float4 ov;
    ov.x = acc.x + c0*we0.x + c1*we1.x + c2*we2.x;
    ov.y = acc.y + c0*we0.y + c1*we1.y + c2*we2.y;
    ov.z = acc.z + c0*we0.z + c1*we1.z + c2*we2.z;
    ov.w = acc.w + c0*we0.w + c1*we1.w + c2*we2.w;
    *(float4*)(aog + (i0+w)*INNER + qb + dq) = ov;
  }
}

// ---- fused per-row layer tail: Wo+gate1+LN2+FFN+gate2 (+next QKV | energy) ----
__global__ __launch_bounds__(512) void k_layer(
    float* nodes, const float* __restrict__ aog,
    float* qg_n, float* kT_n, float* vg_n,
    const float* __restrict__ Wo, const float* __restrict__ bo,
    const float* __restrict__ Wg1,
    const float* __restrict__ ln2_g, const float* __restrict__ ln2_b,
    const float* __restrict__ W1, const float* __restrict__ b1,
    const float* __restrict__ W2, const float* __restrict__ b2,
    const float* __restrict__ Wg2,
    const float* __restrict__ ln1_g_n, const float* __restrict__ ln1_b_n,
    const float* __restrict__ Wq_n, const float* __restrict__ bq_n,
    const float* __restrict__ Wkv_n, const float* __restrict__ bkv_n,
    const float* __restrict__ be_n,
    const float* __restrict__ out_w, const float* __restrict__ out_b,
    float* eout, int has_next)
{
  __shared__ __align__(16) float stg[16384];  // 64KB double-buffered weight staging
  __shared__ __align__(16) float SC[2048];    // matvec partials
  __shared__ __align__(16) float qs[INNER];   // FFN hidden
  __shared__ __align__(16) float aos[INNER];  // attention output row
  __shared__ __align__(16) float xsm[DIM];
  const int t = threadIdx.x, i = blockIdx.x;
  const int w = t>>6, l = t&63;

  aos[t] = aog[i*INNER + t];
  float nd0 = nodes[i*DIM + l];        // per-wave redundant row state
  float nd1 = nodes[i*DIM + 64 + l];
  __syncthreads();

  // ---- Wo (staged) + gate1 + LN2 ----
  mv_staged<128,8>(aos, Wo, stg, SC, t);
  {
    float o0 = bo[l], o1 = bo[64+l];
#pragma unroll
    for(int fg=0; fg<16; fg++){ o0 += SC[fg*DIM + l]; o1 += SC[fg*DIM + 64 + l]; }
    gate_wave(o0, o1, nd0, nd1, Wg1, l);
    float x0, x1;
    ln_wave(nd0, nd1, ln2_g, ln2_b, l, x0, x1);
    xsm[l] = x0; xsm[64+l] = x1;
  }
  // (mv_staged internal barriers order xsm/SC reuse)

  // ---- FFN (staged) ----
  mv_staged<512,8>(xsm, W1, stg, SC, t);
  {
    float a = b1[t] + SC[t] + SC[INNER+t] + SC[2*INNER+t] + SC[3*INNER+t];
    qs[t] = 0.5f*a*(1.f + erff(a*0.70710678118654752440f));
  }
  mv_staged<128,8>(qs, W2, stg, SC, t);
  {
    float y0 = b2[l], y1 = b2[64+l];
#pragma unroll
    for(int fg=0; fg<16; fg++){ y0 += SC[fg*DIM + l]; y1 += SC[fg*DIM + 64 + l]; }
    gate_wave(y0, y1, nd0, nd1, Wg2, l);
    if(w==0){ nodes[i*DIM + l] = nd0; nodes[i*DIM + 64 + l] = nd1; }
    if(has_next){
      float x0, x1;
      ln_wave(nd0, nd1, ln1_g_n, ln1_b_n, l, x0, x1);
      xsm[l] = x0; xsm[64+l] = x1;
    } else if(w==0){
      float ev = nd0*out_w[l] + nd1*out_w[64+l];
      ev = wred_sum(ev);
      if(l==0) eout[i] = ev + out_b[0];
    }
  }
  if(has_next){
    qkv_tail(xsm, i, Wq_n, bq_n, Wkv_n, bkv_n, be_n,
             qg_n, kT_n, vg_n, stg, SC, t);
  }
}

extern "C" void kernel_launch(void* const* d_in, const int* in_sizes, int n_in,
                              void* d_out, int out_size, void* d_ws, size_t ws_size,
                              hipStream_t stream){
  const float* coords   = (const float*)d_in[0];
  const int*   bonds    = (const int*  )d_in[1];
  const float* noise    = (const float*)d_in[2];
  const float* atom_emb = (const float*)d_in[3];
  const float* ln1_g = (const float*)d_in[4];
  const float* ln1_b = (const float*)d_in[5];
  const float* Wq    = (const float*)d_in[6];
  const float* bq    = (const float*)d_in[7];
  const float* Wkv   = (const float*)d_in[8];
  const float* bkv   = (const float*)d_in[9];
  const float* We    = (const float*)d_in[10];
  const float* be    = (const float*)d_in[11];
  const float* Wo    = (const float*)d_in[12];
  const float* bo    = (const float*)d_in[13];
  const float* Wg1   = (const float*)d_in[14];
  const float* ln2_g = (const float*)d_in[15];
  const float* ln2_b = (const float*)d_in[16];
  const float* W1    = (const float*)d_in[17];
  const float* b1    = (const float*)d_in[18];
  const float* W2    = (const float*)d_in[19];
  const float* b2    = (const float*)d_in[20];
  const float* Wg2   = (const float*)d_in[21];
  const float* out_w = (const float*)d_in[22];
  const float* out_b = (const float*)d_in[23];

  // workspace (fp32): ~3.7 MB
  float* ws = (float*)d_ws;
  float* nodes   = ws;                              // 32768 floats
  float* qbuf[2] = { ws +  32768, ws + 163840 };    // 131072 each
  float* kbuf[2] = { ws + 294912, ws + 425984 };    // transposed [c][j]
  float* vbuf[2] = { ws + 557056, ws + 688128 };    // row-major [j][c]
  float* aobuf   = ws + 819200;                     // 131072 (attention out)

  k_qkv0<<<NN, 512, 0, stream>>>(atom_emb, noise, nodes, ln1_g, ln1_b,
                                 Wq, bq, Wkv, bkv, be,
                                 qbuf[0], kbuf[0], vbuf[0]);
  for(int l=0; l<DEPTH; l++){
    int cur = l&1, nxt = cur^1;
    int has_next = (l < DEPTH-1);
    int ln = has_next ? l+1 : l;    // keep pointers valid when unused
    k_attn<<<NN, 512, 0, stream>>>(
      qbuf[cur], kbuf[cur], vbuf[cur], bonds, coords,
      We + (size_t)l*3*INNER, aobuf);
    k_layer<<<NN, 512, 0, stream>>>(
      nodes, aobuf,
      qbuf[nxt], kbuf[nxt], vbuf[nxt],
      Wo  + (size_t)l*INNER*DIM, bo + (size_t)l*DIM, Wg1 + (size_t)l*3*DIM,
      ln2_g + (size_t)l*DIM, ln2_b + (size_t)l*DIM,
      W1  + (size_t)l*DIM*4*DIM, b1 + (size_t)l*4*DIM,
      W2  + (size_t)l*4*DIM*DIM, b2 + (size_t)l*DIM, Wg2 + (size_t)l*3*DIM,
      ln1_g + (size_t)ln*DIM, ln1_b + (size_t)ln*DIM,
      Wq  + (size_t)ln*DIM*INNER, bq + (size_t)ln*INNER,
      Wkv + (size_t)ln*DIM*2*INNER, bkv + (size_t)ln*2*INNER,
      be  + (size_t)ln*INNER,
      out_w, out_b, (float*)d_out, has_next);
  }
}

// Round 10
// 296.323 us; speedup vs baseline: 1.2974x; 1.2974x over previous
//
#include <hip/hip_runtime.h>

#define NN     256
#define NF     127
#define DIM    128
#define NH     8
#define DH     64
#define INNER  512
#define DEPTH  6
#define NB     512
#define ATTN_SCALE 0.125f
#define LN_EPS 1e-5f

#define FMA4(A_, S_, V_) { A_.x=fmaf(S_,(V_).x,A_.x); A_.y=fmaf(S_,(V_).y,A_.y); \
                           A_.z=fmaf(S_,(V_).z,A_.z); A_.w=fmaf(S_,(V_).w,A_.w); }

__device__ __forceinline__ float wred_sum(float v){
#pragma unroll
  for(int o=32;o;o>>=1) v += __shfl_xor(v,o);
  return v;
}
__device__ __forceinline__ float wred_max(float v){
#pragma unroll
  for(int o=32;o;o>>=1) v = fmaxf(v,__shfl_xor(v,o));
  return v;
}
__device__ __forceinline__ float2 wred_sum2(float a, float b){
#pragma unroll
  for(int o=32;o;o>>=1){ a += __shfl_xor(a,o); b += __shfl_xor(b,o); }
  return make_float2(a,b);
}

// In-wave LayerNorm of a 128-dim row held as (n0,n1) = dims (l, l+64) per lane.
__device__ __forceinline__ void ln_wave(float n0, float n1,
                                        const float* g, const float* b, int l,
                                        float& x0, float& x1){
  float2 sv = wred_sum2(n0+n1, n0*n0+n1*n1);
  float m  = sv.x*(1.f/DIM);
  float var = sv.y*(1.f/DIM) - m*m;
  float rs = rsqrtf(var + LN_EPS);
  x0 = (n0-m)*rs*g[l]    + b[l];
  x1 = (n1-m)*rs*g[64+l] + b[64+l];
}

// In-wave gated residual. No barriers.
__device__ __forceinline__ void gate_wave(float o0, float o1, float& n0, float& n1,
                                          const float* Wg, int l){
  float gv = o0*Wg[l]    + n0*Wg[DIM+l]    + (o0-n0)*Wg[2*DIM+l]
           + o1*Wg[64+l] + n1*Wg[DIM+64+l] + (o1-n1)*Wg[2*DIM+64+l];
  gv = wred_sum(gv);
  float gate = 1.f/(1.f + expf(-gv));
  n0 = o0*gate + n0*(1.f-gate);
  n1 = o1*gate + n1*(1.f-gate);
}

// ---- matvec partials, 512-thread variants (SC = 2048 floats) ----
// x[128] @ W[128][512] -> SC[fq*512+c], fq in [0,4)
__device__ __forceinline__ void mvp128_512(const float* xin, const float* W,
                                           float* SC, int t){
  const int cg4 = (t&127)<<2, fq = t>>7;
  float4 acc = make_float4(0.f,0.f,0.f,0.f);
#pragma unroll 8
  for(int f=fq*32; f<fq*32+32; f++){
    float4 wv = *(const float4*)(W + f*INNER + cg4);
    float xv = xin[f];
    FMA4(acc, xv, wv);
  }
  *(float4*)(SC + fq*INNER + cg4) = acc;
}
// x[128] @ W[128][1024] -> SC[rh*1024+c], rh in [0,2)
__device__ __forceinline__ void mvp128_1024(const float* xin, const float* W,
                                            float* SC, int t){
  const int cg4 = (t&255)<<2, rh = t>>8;
  float4 acc = make_float4(0.f,0.f,0.f,0.f);
#pragma unroll 8
  for(int f=rh*64; f<rh*64+64; f++){
    float4 wv = *(const float4*)(W + f*(2*INNER) + cg4);
    float xv = xin[f];
    FMA4(acc, xv, wv);
  }
  *(float4*)(SC + rh*(2*INNER) + cg4) = acc;
}
// a[512] @ W[512][128] -> SC[fg*128+c], fg in [0,16)
__device__ __forceinline__ void mvp512_128(const float* ain, const float* W,
                                           float* SC, int t){
  const int cg4 = (t&31)<<2, fg = t>>5;
  float4 acc = make_float4(0.f,0.f,0.f,0.f);
#pragma unroll 8
  for(int f=fg*32; f<fg*32+32; f++){
    float4 wv = *(const float4*)(W + f*DIM + cg4);
    float av = ain[f];
    FMA4(acc, av, wv);
  }
  *(float4*)(SC + fg*DIM + cg4) = acc;
}

// LN1 output xs[128] (LDS) -> next-layer q/k/v. 3 barriers inside.
__device__ __forceinline__ void qkv_tail(const float* xs, int i,
    const float* Wq, const float* bq, const float* Wkv, const float* bkv,
    const float* be, float* qgn, float* kTn, float* vgn, float* SC, int t){
  mvp128_512(xs, Wq, SC, t);
  __syncthreads();
  qgn[i*INNER + t] = bq[t] + SC[t] + SC[INNER+t] + SC[2*INNER+t] + SC[3*INNER+t];
  __syncthreads();                 // SC reuse
  mvp128_1024(xs, Wkv, SC, t);
  __syncthreads();
#pragma unroll
  for(int cc=0; cc<2; cc++){
    int c = t + cc*512;
    float s = bkv[c] + SC[c] + SC[2*INNER+c];
    if(c < INNER) kTn[c*NN + i]            = s + be[c];
    else          vgn[i*INNER + c - INNER] = s + be[c-INNER];
  }
}

// ---- layer 0: node-init + LN1 + QKV (blocks 0..255); edge-plane build (256..287) ----
__global__ __launch_bounds__(512) void k_qkv0(const float* atom_emb, const float* noise,
    float* nodes, const float* ln1_g, const float* ln1_b,
    const float* Wq, const float* bq, const float* Wkv, const float* bkv, const float* be,
    float* qg, float* kT, float* vg,
    const int* bonds, const float* coords, float* ebg){
  __shared__ __align__(16) float SC[2048];
  __shared__ __align__(16) float xsm[DIM];
  __shared__ __align__(16) float ebs[8*768];
  const int t = threadIdx.x, bid = blockIdx.x;
  if(bid >= NN){
    // build layer-invariant edge planes for rows i0..i0+7 -> global ebg
    const int i0 = (bid-NN)<<3;
#pragma unroll
    for(int cc=0; cc<12; cc++) ebs[cc*512 + t] = 0.f;
    __syncthreads();
    {
      const int bi = bonds[2*t], bj = bonds[2*t+1];
      const bool hi = (bi>=i0 && bi<i0+8), hj = (bj>=i0 && bj<i0+8);
      if(hi || hj){
        float dx = coords[3*bi+0] - coords[3*bj+0];
        float dy = coords[3*bi+1] - coords[3*bj+1];
        float dz = coords[3*bi+2] - coords[3*bj+2];
        if(hi){ float* e = ebs + (bi-i0)*768; e[bj]=dx;  e[256+bj]=dy;  e[512+bj]=dz;  }
        if(hj){ float* e = ebs + (bj-i0)*768; e[bi]=-dx; e[256+bi]=-dy; e[512+bi]=-dz; }
      }
    }
    __syncthreads();
#pragma unroll
    for(int cc=0; cc<12; cc++) ebg[(size_t)i0*768 + cc*512 + t] = ebs[cc*512 + t];
    return;
  }
  const int i = bid, w = t>>6, l = t&63;
  float nd0 = (l<NF)?    atom_emb[i*NF + l]      : noise[0];
  float nd1 = (64+l<NF)? atom_emb[i*NF + 64 + l] : noise[0];
  if(w==0){ nodes[i*DIM + l] = nd0; nodes[i*DIM + 64 + l] = nd1; }
  float x0, x1;
  ln_wave(nd0, nd1, ln1_g, ln1_b, l, x0, x1);
  xsm[l] = x0; xsm[64+l] = x1;     // all waves write identical values (benign)
  __syncthreads();
  qkv_tail(xsm, i, Wq, bq, Wkv, bkv, be, qg, kT, vg, SC, t);
}

// ---- attention kernel: block = (head h, 8-row tile); wave w = row i0+w ----
// Also L2-prefetches the upcoming k_layer's weight stream (this XCD's slice).
__global__ __launch_bounds__(512) void k_attn(
    const float* __restrict__ qg, const float* __restrict__ kT,
    const float* __restrict__ vg, const float* __restrict__ ebg,
    const float* __restrict__ We, float* __restrict__ aog,
    const float* __restrict__ pfA, const float* __restrict__ pfB,
    const float* __restrict__ pfC, const float* __restrict__ pfD,
    const float* __restrict__ pfE, int pf_next)
{
  __shared__ __align__(16) float qsm[8*DH];     // q head-slice, 8 rows
  __shared__ __align__(16) float aW[8][NN];     // attn weights per row
  const int t = threadIdx.x;
  const int h = blockIdx.x >> 5, i0 = (blockIdx.x & 31) << 3;
  const int w = t>>6, l = t&63;
  const int qb = h*DH, j0 = l<<2;

  qsm[w*DH + l] = qg[(i0+w)*INNER + qb + l];

  // ---- L2 warm: blocks with bid&7==x share XCD x; slice s=bid>>3 covers 1/32 of
  // each weight array -> the 32 blocks per XCD pull the full 1.5MB into their L2.
  {
    const int s = blockIdx.x >> 3;
    float keep = 0.f;
    { float4 v = ((const float4*)pfA)[s*512 + t];  keep += v.x+v.y+v.z+v.w; } // Wo  (64K floats)
    { float4 v = ((const float4*)pfB)[s*512 + t];  keep += v.x+v.y+v.z+v.w; } // W1
    { float4 v = ((const float4*)pfC)[s*512 + t];  keep += v.x+v.y+v.z+v.w; } // W2
    if(pf_next){
      { float4 v = ((const float4*)pfD)[s*512 + t];        keep += v.x+v.y+v.z+v.w; } // Wq'
      { float4 v = ((const float4*)pfE)[s*1024 + t];       keep += v.x+v.y+v.z+v.w; } // Wkv' lo
      { float4 v = ((const float4*)pfE)[s*1024 + 512 + t]; keep += v.x+v.y+v.z+v.w; } // Wkv' hi
    }
    asm volatile("" :: "v"(keep));   // keep loads live (rule #17) without a store
  }
  __syncthreads();

  // qwe_c = q_row . We[c, h-slice]  (in-wave butterfly)
  float qwe0, qwe1, qwe2;
  {
    float qv = qsm[w*DH + l];
    qwe0 = qv*We[0*INNER + qb + l];
    qwe1 = qv*We[1*INNER + qb + l];
    qwe2 = qv*We[2*INNER + qb + l];
#pragma unroll
    for(int o=32;o;o>>=1){
      qwe0 += __shfl_xor(qwe0,o); qwe1 += __shfl_xor(qwe1,o); qwe2 += __shfl_xor(qwe2,o);
    }
  }
  // QK^T: lane l -> scores j0..j0+3 for row i0+w
  const float* __restrict__ kTh = kT + qb*NN;
  float s0=0.f,s1=0.f,s2=0.f,s3=0.f;
#pragma unroll 8
  for(int o=0;o<DH;o++){
    float qv = qsm[w*DH + o];
    float4 kk = *(const float4*)(kTh + o*NN + j0);
    s0=fmaf(qv,kk.x,s0); s1=fmaf(qv,kk.y,s1); s2=fmaf(qv,kk.z,s2); s3=fmaf(qv,kk.w,s3);
  }
  const float* __restrict__ e = ebg + (size_t)(i0+w)*768;
  float4 ex = *(const float4*)(e + j0);
  float4 ey = *(const float4*)(e + 256 + j0);
  float4 ez = *(const float4*)(e + 512 + j0);
  s0 = (s0 + qwe0*ex.x + qwe1*ey.x + qwe2*ez.x)*ATTN_SCALE;
  s1 = (s1 + qwe0*ex.y + qwe1*ey.y + qwe2*ez.y)*ATTN_SCALE;
  s2 = (s2 + qwe0*ex.z + qwe1*ey.z + qwe2*ez.z)*ATTN_SCALE;
  s3 = (s3 + qwe0*ex.w + qwe1*ey.w + qwe2*ez.w)*ATTN_SCALE;
  float mx = wred_max(fmaxf(fmaxf(s0,s1),fmaxf(s2,s3)));
  float p0=expf(s0-mx), p1=expf(s1-mx), p2=expf(s2-mx), p3=expf(s3-mx);
  float inv = 1.f / wred_sum(p0+p1+p2+p3);
  float a0=p0*inv, a1=p1*inv, a2=p2*inv, a3=p3*inv;
  *(float4*)(aW[w] + j0) = make_float4(a0,a1,a2,a3);
  // edge moments c_c = sum_j a_j * e[c][j]
  float c0 = a0*ex.x + a1*ex.y + a2*ex.z + a3*ex.w;
  float c1 = a0*ey.x + a1*ey.y + a2*ey.z + a3*ey.w;
  float c2 = a0*ez.x + a1*ez.y + a2*ez.z + a3*ez.w;
  c0 = wred_sum(c0); c1 = wred_sum(c1); c2 = wred_sum(c2);
  __builtin_amdgcn_wave_barrier();   // order aW writes before same-wave aW reads
  // PV: lane l -> dims dq..dq+3, rotated j-start spreads aW banks
  const int dq = (l&15)<<2, jg = l>>4;
  const float* __restrict__ vb = vg + qb + dq;
  float4 acc = make_float4(0.f,0.f,0.f,0.f);
#pragma unroll 8
  for(int jj=0;jj<64;jj++){
    int j = (jg<<6) + ((jj + (jg<<3)) & 63);
    float a = aW[w][j];
    float4 vv = *(const float4*)(vb + j*INNER);
    FMA4(acc, a, vv);
  }
#pragma unroll
  for(int o=16;o<64;o<<=1){
    acc.x += __shfl_xor(acc.x,o); acc.y += __shfl_xor(acc.y,o);
    acc.z += __shfl_xor(acc.z,o); acc.w += __shfl_xor(acc.w,o);
  }
  if(l<16){
    float4 we0 = *(const float4*)(We + 0*INNER + qb + dq);
    float4 we1 = *(const float4*)(We + 1*INNER + qb + dq);
    float4 we2 = *(const float4*)(We + 2*INNER + qb + dq);
    float4 ov;
    ov.x = acc.x + c0*we0.x + c1*we1.x + c2*we2.x;
    ov.y = acc.y + c0*we0.y + c1*we1.y + c2*we2.y;
    ov.z = acc.z + c0*we0.z + c1*we1.z + c2*we2.z;
    ov.w = acc.w + c0*we0.w + c1*we1.w + c2*we2.w;
    *(float4*)(aog + (i0+w)*INNER + qb + dq) = ov;
  }
}

// ---- fused per-row layer tail: Wo+gate1+LN2+FFN+gate2 (+next QKV | energy) ----
__global__ __launch_bounds__(512) void k_layer(
    float* nodes, const float* __restrict__ aog,
    float* qg_n, float* kT_n, float* vg_n,
    const float* __restrict__ Wo, const float* __restrict__ bo,
    const float* __restrict__ Wg1,
    const float* __restrict__ ln2_g, const float* __restrict__ ln2_b,
    const float* __restrict__ W1, const float* __restrict__ b1,
    const float* __restrict__ W2, const float* __restrict__ b2,
    const float* __restrict__ Wg2,
    const float* __restrict__ ln1_g_n, const float* __restrict__ ln1_b_n,
    const float* __restrict__ Wq_n, const float* __restrict__ bq_n,
    const float* __restrict__ Wkv_n, const float* __restrict__ bkv_n,
    const float* __restrict__ be_n,
    const float* __restrict__ out_w, const float* __restrict__ out_b,
    float* eout, int has_next)
{
  __shared__ __align__(16) float SC[2048];   // matvec partials
  __shared__ __align__(16) float qs[INNER];  // FFN hidden
  __shared__ __align__(16) float aos[INNER]; // attention output row
  __shared__ __align__(16) float xsm[DIM];
  const int t = threadIdx.x, i = blockIdx.x;
  const int w = t>>6, l = t&63;

  aos[t] = aog[i*INNER + t];
  float nd0 = nodes[i*DIM + l];        // per-wave redundant row state
  float nd1 = nodes[i*DIM + 64 + l];
  __syncthreads();                               // B1

  // ---- Wo + gate1 + LN2 ----
  mvp512_128(aos, Wo, SC, t);
  __syncthreads();                               // B2
  {
    float o0 = bo[l], o1 = bo[64+l];
#pragma unroll
    for(int fg=0; fg<16; fg++){ o0 += SC[fg*DIM + l]; o1 += SC[fg*DIM + 64 + l]; }
    gate_wave(o0, o1, nd0, nd1, Wg1, l);
    float x0, x1;
    ln_wave(nd0, nd1, ln2_g, ln2_b, l, x0, x1);
    xsm[l] = x0; xsm[64+l] = x1;
  }
  __syncthreads();                               // B3 (xsm ready; SC free)

  // ---- FFN ----
  mvp128_512(xsm, W1, SC, t);
  __syncthreads();                               // B4
  {
    float a = b1[t] + SC[t] + SC[INNER+t] + SC[2*INNER+t] + SC[3*INNER+t];
    qs[t] = 0.5f*a*(1.f + erff(a*0.70710678118654752440f));
  }
  __syncthreads();                               // B5 (hidden ready; SC free)
  mvp512_128(qs, W2, SC, t);
  __syncthreads();                               // B6
  {
    float y0 = b2[l], y1 = b2[64+l];
#pragma unroll
    for(int fg=0; fg<16; fg++){ y0 += SC[fg*DIM + l]; y1 += SC[fg*DIM + 64 + l]; }
    gate_wave(y0, y1, nd0, nd1, Wg2, l);
    if(w==0){ nodes[i*DIM + l] = nd0; nodes[i*DIM + 64 + l] = nd1; }
    if(has_next){
      float x0, x1;
      ln_wave(nd0, nd1, ln1_g_n, ln1_b_n, l, x0, x1);
      xsm[l] = x0; xsm[64+l] = x1;
    } else if(w==0){
      float ev = nd0*out_w[l] + nd1*out_w[64+l];
      ev = wred_sum(ev);
      if(l==0) eout[i] = ev + out_b[0];
    }
  }
  if(has_next){
    __syncthreads();                             // B7 (xsm ready; SC free)
    qkv_tail(xsm, i, Wq_n, bq_n, Wkv_n, bkv_n, be_n,
             qg_n, kT_n, vg_n, SC, t);           // B8-B10
  }
}

extern "C" void kernel_launch(void* const* d_in, const int* in_sizes, int n_in,
                              void* d_out, int out_size, void* d_ws, size_t ws_size,
                              hipStream_t stream){
  const float* coords   = (const float*)d_in[0];
  const int*   bonds    = (const int*  )d_in[1];
  const float* noise    = (const float*)d_in[2];
  const float* atom_emb = (const float*)d_in[3];
  const float* ln1_g = (const float*)d_in[4];
  const float* ln1_b = (const float*)d_in[5];
  const float* Wq    = (const float*)d_in[6];
  const float* bq    = (const float*)d_in[7];
  const float* Wkv   = (const float*)d_in[8];
  const float* bkv   = (const float*)d_in[9];
  const float* We    = (const float*)d_in[10];
  const float* be    = (const float*)d_in[11];
  const float* Wo    = (const float*)d_in[12];
  const float* bo    = (const float*)d_in[13];
  const float* Wg1   = (const float*)d_in[14];
  const float* ln2_g = (const float*)d_in[15];
  const float* ln2_b = (const float*)d_in[16];
  const float* W1    = (const float*)d_in[17];
  const float* b1    = (const float*)d_in[18];
  const float* W2    = (const float*)d_in[19];
  const float* b2    = (const float*)d_in[20];
  const float* Wg2   = (const float*)d_in[21];
  const float* out_w = (const float*)d_in[22];
  const float* out_b = (const float*)d_in[23];

  // workspace (fp32): ~4.6 MB
  float* ws = (float*)d_ws;
  float* nodes   = ws;                              // 32768 floats
  float* qbuf[2] = { ws +  32768, ws + 163840 };    // 131072 each
  float* kbuf[2] = { ws + 294912, ws + 425984 };    // transposed [c][j]
  float* vbuf[2] = { ws + 557056, ws + 688128 };    // row-major [j][c]
  float* aobuf   = ws + 819200;                     // 131072 (attention out)
  float* ebg     = ws + 950272;                     // 196608 (edge planes, layer-invariant)

  k_qkv0<<<NN+32, 512, 0, stream>>>(atom_emb, noise, nodes, ln1_g, ln1_b,
                                    Wq, bq, Wkv, bkv, be,
                                    qbuf[0], kbuf[0], vbuf[0],
                                    bonds, coords, ebg);
  for(int l=0; l<DEPTH; l++){
    int cur = l&1, nxt = cur^1;
    int has_next = (l < DEPTH-1);
    int ln = has_next ? l+1 : l;    // keep pointers valid when unused
    const float* Wo_l = Wo + (size_t)l*INNER*DIM;
    const float* W1_l = W1 + (size_t)l*DIM*4*DIM;
    const float* W2_l = W2 + (size_t)l*4*DIM*DIM;
    const float* Wq_n = Wq  + (size_t)ln*DIM*INNER;
    const float* Wkv_n= Wkv + (size_t)ln*DIM*2*INNER;
    k_attn<<<NN, 512, 0, stream>>>(
      qbuf[cur], kbuf[cur], vbuf[cur], ebg,
      We + (size_t)l*3*INNER, aobuf,
      Wo_l, W1_l, W2_l, Wq_n, Wkv_n, has_next);
    k_layer<<<NN, 512, 0, stream>>>(
      nodes, aobuf,
      qbuf[nxt], kbuf[nxt], vbuf[nxt],
      Wo_l, bo + (size_t)l*DIM, Wg1 + (size_t)l*3*DIM,
      ln2_g + (size_t)l*DIM, ln2_b + (size_t)l*DIM,
      W1_l, b1 + (size_t)l*4*DIM,
      W2_l, b2 + (size_t)l*DIM, Wg2 + (size_t)l*3*DIM,
      ln1_g + (size_t)ln*DIM, ln1_b + (size_t)ln*DIM,
      Wq_n, bq + (size_t)ln*INNER,
      Wkv_n, bkv + (size_t)ln*2*INNER,
      be  + (size_t)ln*INNER,
      out_w, out_b, (float*)d_out, has_next);
  }
}

// Round 12
// 286.500 us; speedup vs baseline: 1.3419x; 1.0343x over previous
//
#include <hip/hip_runtime.h>

#define NN     256
#define NF     127
#define DIM    128
#define NH     8
#define DH     64
#define INNER  512
#define DEPTH  6
#define NB     512
#define ATTN_SCALE 0.125f
#define LN_EPS 1e-5f

typedef _Float16 f16;
union H8 { uint4 u; f16 h[8]; };

#define FMA4(A_, S_, V_) { A_.x=fmaf(S_,(V_).x,A_.x); A_.y=fmaf(S_,(V_).y,A_.y); \
                           A_.z=fmaf(S_,(V_).z,A_.z); A_.w=fmaf(S_,(V_).w,A_.w); }

__device__ __forceinline__ float wred_sum(float v){
#pragma unroll
  for(int o=32;o;o>>=1) v += __shfl_xor(v,o);
  return v;
}
__device__ __forceinline__ float wred_max(float v){
#pragma unroll
  for(int o=32;o;o>>=1) v = fmaxf(v,__shfl_xor(v,o));
  return v;
}
__device__ __forceinline__ float2 wred_sum2(float a, float b){
#pragma unroll
  for(int o=32;o;o>>=1){ a += __shfl_xor(a,o); b += __shfl_xor(b,o); }
  return make_float2(a,b);
}

// In-wave LayerNorm of a 128-dim row held as (n0,n1) = dims (l, l+64) per lane.
__device__ __forceinline__ void ln_wave(float n0, float n1,
                                        const float* g, const float* b, int l,
                                        float& x0, float& x1){
  float2 sv = wred_sum2(n0+n1, n0*n0+n1*n1);
  float m  = sv.x*(1.f/DIM);
  float var = sv.y*(1.f/DIM) - m*m;
  float rs = rsqrtf(var + LN_EPS);
  x0 = (n0-m)*rs*g[l]    + b[l];
  x1 = (n1-m)*rs*g[64+l] + b[64+l];
}

// In-wave gated residual. No barriers.
__device__ __forceinline__ void gate_wave(float o0, float o1, float& n0, float& n1,
                                          const float* Wg, int l){
  float gv = o0*Wg[l]    + n0*Wg[DIM+l]    + (o0-n0)*Wg[2*DIM+l]
           + o1*Wg[64+l] + n1*Wg[DIM+64+l] + (o1-n1)*Wg[2*DIM+64+l];
  gv = wred_sum(gv);
  float gate = 1.f/(1.f + expf(-gv));
  n0 = o0*gate + n0*(1.f-gate);
  n1 = o1*gate + n1*(1.f-gate);
}

// ---- fp16-weight matvec partials ----
// x[128] @ W[128][512]h -> SC[fg*512+c], fg in [0,8)
__device__ __forceinline__ void mvp128_512h(const float* __restrict__ xin,
                                            const f16* __restrict__ W,
                                            float* __restrict__ SC, int t){
  const int cg8 = (t&63)<<3, fg = t>>6, f0 = fg<<4;
  const f16* __restrict__ p = W + f0*INNER + cg8;
  float4 a0 = make_float4(0.f,0.f,0.f,0.f), a1 = a0;
#pragma unroll
  for(int k=0;k<16;k++){
    H8 wv; wv.u = *(const uint4*)(p + k*INNER);
    float x = xin[f0+k];
    a0.x=fmaf(x,(float)wv.h[0],a0.x); a0.y=fmaf(x,(float)wv.h[1],a0.y);
    a0.z=fmaf(x,(float)wv.h[2],a0.z); a0.w=fmaf(x,(float)wv.h[3],a0.w);
    a1.x=fmaf(x,(float)wv.h[4],a1.x); a1.y=fmaf(x,(float)wv.h[5],a1.y);
    a1.z=fmaf(x,(float)wv.h[6],a1.z); a1.w=fmaf(x,(float)wv.h[7],a1.w);
  }
  *(float4*)(SC + fg*INNER + cg8)     = a0;
  *(float4*)(SC + fg*INNER + cg8 + 4) = a1;
}
// a[512] @ W[512][128]h -> SC[fg*128+c], fg in [0,32)
__device__ __forceinline__ void mvp512_128h(const float* __restrict__ ain,
                                            const f16* __restrict__ W,
                                            float* __restrict__ SC, int t){
  const int cg8 = (t&15)<<3, fg = t>>4, f0 = fg<<4;
  const f16* __restrict__ p = W + f0*DIM + cg8;
  float4 a0 = make_float4(0.f,0.f,0.f,0.f), a1 = a0;
#pragma unroll
  for(int k=0;k<16;k++){
    H8 wv; wv.u = *(const uint4*)(p + k*DIM);
    float x = ain[f0+k];
    a0.x=fmaf(x,(float)wv.h[0],a0.x); a0.y=fmaf(x,(float)wv.h[1],a0.y);
    a0.z=fmaf(x,(float)wv.h[2],a0.z); a0.w=fmaf(x,(float)wv.h[3],a0.w);
    a1.x=fmaf(x,(float)wv.h[4],a1.x); a1.y=fmaf(x,(float)wv.h[5],a1.y);
    a1.z=fmaf(x,(float)wv.h[6],a1.z); a1.w=fmaf(x,(float)wv.h[7],a1.w);
  }
  *(float4*)(SC + fg*DIM + cg8)     = a0;
  *(float4*)(SC + fg*DIM + cg8 + 4) = a1;
}
// fp32: x[128] @ W[128][1024] -> SC[rh*1024+c], rh in [0,2)
__device__ __forceinline__ void mvp128_1024(const float* __restrict__ xin,
                                            const float* __restrict__ W,
                                            float* __restrict__ SC, int t){
  const int cg4 = (t&255)<<2, rh = t>>8;
  float4 acc = make_float4(0.f,0.f,0.f,0.f);
#pragma unroll 8
  for(int f=rh*64; f<rh*64+64; f++){
    float4 wv = *(const float4*)(W + f*(2*INNER) + cg4);
    float xv = xin[f];
    FMA4(acc, xv, wv);
  }
  *(float4*)(SC + rh*(2*INNER) + cg4) = acc;
}

// LN1 output xs[128] (LDS) -> q/k/v for row i. Wq fp16, Wkv fp32, K/V fp32 out.
// SC: 6144 floats. 1 barrier inside.
__device__ __forceinline__ void qkv_tail(const float* __restrict__ xs, int i,
    const f16* __restrict__ Wqh, const float* __restrict__ bq,
    const float* __restrict__ Wkv, const float* __restrict__ bkv,
    const float* __restrict__ be, float* qgn, float* kTn, float* vgn,
    float* __restrict__ SC, int t){
  mvp128_512h(xs, Wqh, SC,        t);   // SC[0..4096)
  mvp128_1024(xs, Wkv, SC + 4096, t);   // SC[4096..6144)
  __syncthreads();
  {
    float s = bq[t];
#pragma unroll
    for(int fg=0; fg<8; fg++) s += SC[fg*INNER + t];
    qgn[i*INNER + t] = s;
  }
#pragma unroll
  for(int cc=0; cc<2; cc++){
    int c = t + cc*512;
    float sv = bkv[c] + SC[4096 + c] + SC[4096 + 1024 + c];
    if(c < INNER) kTn[c*NN + i]            = sv + be[c];
    else          vgn[i*INNER + c - INNER] = sv + be[c-INNER];
  }
}

// ---- prep: fp32->fp16 conversion of Wq, Wo, W1, W2 only ----
__global__ __launch_bounds__(512) void k_prep(
    const float* __restrict__ Wq, const float* __restrict__ Wo,
    const float* __restrict__ W1, const float* __restrict__ W2,
    f16* Wqh, f16* Woh, f16* W1h, f16* W2h)
{
  const int NQ = DEPTH*DIM*INNER;        // 393216
  const int NTOT = 4*NQ;                 // 1572864
  for(int k = blockIdx.x*512 + threadIdx.x; k < NTOT; k += gridDim.x*512){
    float v; f16* dst;
    if(k < NQ)        { v = Wq[k];        dst = Wqh + k; }
    else if(k < 2*NQ) { v = Wo[k-NQ];     dst = Woh + (k-NQ); }
    else if(k < 3*NQ) { v = W1[k-2*NQ];   dst = W1h + (k-2*NQ); }
    else              { v = W2[k-3*NQ];   dst = W2h + (k-3*NQ); }
    *dst = (f16)v;
  }
}

// ---- layer 0: node-init + LN1 + QKV (blocks 0..255); edge-plane build (256..287) ----
__global__ __launch_bounds__(512) void k_qkv0(const float* atom_emb, const float* noise,
    float* nodes, const float* ln1_g, const float* ln1_b,
    const f16* Wqh, const float* bq, const float* Wkv, const float* bkv, const float* be,
    float* qg, float* kT, float* vg,
    const int* bonds, const float* coords, float* ebg){
  __shared__ __align__(16) float SC[6144];
  __shared__ __align__(16) float xsm[DIM];
  __shared__ __align__(16) float ebs[8*768];
  const int t = threadIdx.x, bid = blockIdx.x;
  if(bid >= NN){
    // build layer-invariant edge planes for rows i0..i0+7 -> global ebg
    const int i0 = (bid-NN)<<3;
#pragma unroll
    for(int cc=0; cc<12; cc++) ebs[cc*512 + t] = 0.f;
    __syncthreads();
    {
      const int bi = bonds[2*t], bj = bonds[2*t+1];
      const bool hi = (bi>=i0 && bi<i0+8), hj = (bj>=i0 && bj<i0+8);
      if(hi || hj){
        float dx = coords[3*bi+0] - coords[3*bj+0];
        float dy = coords[3*bi+1] - coords[3*bj+1];
        float dz = coords[3*bi+2] - coords[3*bj+2];
        if(hi){ float* e = ebs + (bi-i0)*768; e[bj]=dx;  e[256+bj]=dy;  e[512+bj]=dz;  }
        if(hj){ float* e = ebs + (bj-i0)*768; e[bi]=-dx; e[256+bi]=-dy; e[512+bi]=-dz; }
      }
    }
    __syncthreads();
#pragma unroll
    for(int cc=0; cc<12; cc++) ebg[(size_t)i0*768 + cc*512 + t] = ebs[cc*512 + t];
    return;
  }
  const int i = bid, w = t>>6, l = t&63;
  float nd0 = (l<NF)?    atom_emb[i*NF + l]      : noise[0];
  float nd1 = (64+l<NF)? atom_emb[i*NF + 64 + l] : noise[0];
  if(w==0){ nodes[i*DIM + l] = nd0; nodes[i*DIM + 64 + l] = nd1; }
  float x0, x1;
  ln_wave(nd0, nd1, ln1_g, ln1_b, l, x0, x1);
  xsm[l] = x0; xsm[64+l] = x1;     // all waves write identical values (benign)
  __syncthreads();
  qkv_tail(xsm, i, Wqh, bq, Wkv, bkv, be, qg, kT, vg, SC, t);
}

// ---- attention: block = (head h, 8-row tile); wave w = row i0+w; fp32 K/V ----
// Also L2-warms the upcoming k_layer's weight stream (this XCD's slice).
__global__ __launch_bounds__(512) void k_attn(
    const float* __restrict__ qg, const float* __restrict__ kT,
    const float* __restrict__ vg, const float* __restrict__ ebg,
    const float* __restrict__ We, float* __restrict__ aog,
    const f16* __restrict__ pfA, const f16* __restrict__ pfB,
    const f16* __restrict__ pfC, const f16* __restrict__ pfD,
    const float* __restrict__ pfE, int pf_next)
{
  __shared__ __align__(16) float qsm[8*DH];     // q head-slice, 8 rows
  __shared__ __align__(16) float aW[8][NN];     // attn weights per row
  const int t = threadIdx.x;
  const int h = blockIdx.x >> 5, i0 = (blockIdx.x & 31) << 3;
  const int w = t>>6, l = t&63;
  const int qb = h*DH, j0 = l<<2;

  qsm[w*DH + l] = qg[(i0+w)*INNER + qb + l];

  // ---- L2 warm: blocks with bid&7==x share XCD x; slice s=bid>>3 (32 per XCD).
  // fp16 arrays: 128KB/layer -> 4KB slices. Wkv fp32: 512KB -> 16KB slices.
  {
    const int s = blockIdx.x >> 3;
    unsigned keep = 0u;
    if(t < 256){
      keep ^= ((const uint4*)((const char*)pfA + (size_t)s*4096))[t].x;  // Wo_l  (f16)
      keep ^= ((const uint4*)((const char*)pfB + (size_t)s*4096))[t].y;  // W1_l  (f16)
      keep ^= ((const uint4*)((const char*)pfC + (size_t)s*4096))[t].z;  // W2_l  (f16)
      if(pf_next)
        keep ^= ((const uint4*)((const char*)pfD + (size_t)s*4096))[t].w; // Wq'  (f16)
    }
    if(pf_next){
      keep ^= ((const uint4*)((const char*)pfE + (size_t)s*16384))[t].x;       // Wkv' lo
      keep ^= ((const uint4*)((const char*)pfE + (size_t)s*16384))[512 + t].x; // Wkv' hi
    }
    asm volatile("" :: "v"(keep));   // keep touches live (rule #17)
  }
  __syncthreads();

  // qwe_c = q_row . We[c, h-slice]  (in-wave butterfly)
  float qwe0, qwe1, qwe2;
  {
    float qv = qsm[w*DH + l];
    qwe0 = qv*We[0*INNER + qb + l];
    qwe1 = qv*We[1*INNER + qb + l];
    qwe2 = qv*We[2*INNER + qb + l];
#pragma unroll
    for(int o=32;o;o>>=1){
      qwe0 += __shfl_xor(qwe0,o); qwe1 += __shfl_xor(qwe1,o); qwe2 += __shfl_xor(qwe2,o);
    }
  }
  // QK^T: lane l -> scores j0..j0+3 for row i0+w
  const float* __restrict__ kTh = kT + qb*NN;
  float s0=0.f,s1=0.f,s2=0.f,s3=0.f;
#pragma unroll 8
  for(int o=0;o<DH;o++){
    float qv = qsm[w*DH + o];
    float4 kk = *(const float4*)(kTh + o*NN + j0);
    s0=fmaf(qv,kk.x,s0); s1=fmaf(qv,kk.y,s1); s2=fmaf(qv,kk.z,s2); s3=fmaf(qv,kk.w,s3);
  }
  const float* __restrict__ e = ebg + (size_t)(i0+w)*768;
  float4 ex = *(const float4*)(e + j0);
  float4 ey = *(const float4*)(e + 256 + j0);
  float4 ez = *(const float4*)(e + 512 + j0);
  s0 = (s0 + qwe0*ex.x + qwe1*ey.x + qwe2*ez.x)*ATTN_SCALE;
  s1 = (s1 + qwe0*ex.y + qwe1*ey.y + qwe2*ez.y)*ATTN_SCALE;
  s2 = (s2 + qwe0*ex.z + qwe1*ey.z + qwe2*ez.z)*ATTN_SCALE;
  s3 = (s3 + qwe0*ex.w + qwe1*ey.w + qwe2*ez.w)*ATTN_SCALE;
  float mx = wred_max(fmaxf(fmaxf(s0,s1),fmaxf(s2,s3)));
  float p0=expf(s0-mx), p1=expf(s1-mx), p2=expf(s2-mx), p3=expf(s3-mx);
  float inv = 1.f / wred_sum(p0+p1+p2+p3);
  float a0=p0*inv, a1=p1*inv, a2=p2*inv, a3=p3*inv;
  *(float4*)(aW[w] + j0) = make_float4(a0,a1,a2,a3);
  // edge moments c_c = sum_j a_j * e[c][j]
  float c0 = a0*ex.x + a1*ex.y + a2*ex.z + a3*ex.w;
  float c1 = a0*ey.x + a1*ey.y + a2*ey.z + a3*ey.w;
  float c2 = a0*ez.x + a1*ez.y + a2*ez.z + a3*ez.w;
  c0 = wred_sum(c0); c1 = wred_sum(c1); c2 = wred_sum(c2);
  __builtin_amdgcn_wave_barrier();   // order aW writes before same-wave aW reads
  // PV: lane l -> dims dq..dq+3, rotated j-start spreads aW banks
  const int dq = (l&15)<<2, jg = l>>4;
  const float* __restrict__ vb = vg + qb + dq;
  float4 acc = make_float4(0.f,0.f,0.f,0.f);
#pragma unroll 8
  for(int jj=0;jj<64;jj++){
    int j = (jg<<6) + ((jj + (jg<<3)) & 63);
    float a = aW[w][j];
    float4 vv = *(const float4*)(vb + j*INNER);
    FMA4(acc, a, vv);
  }
#pragma unroll
  for(int o=16;o<64;o<<=1){
    acc.x += __shfl_xor(acc.x,o); acc.y += __shfl_xor(acc.y,o);
    acc.z += __shfl_xor(acc.z,o); acc.w += __shfl_xor(acc.w,o);
  }
  if(l<16){
    float4 we0 = *(const float4*)(We + 0*INNER + qb + dq);
    float4 we1 = *(const float4*)(We + 1*INNER + qb + dq);
    float4 we2 = *(const float4*)(We + 2*INNER + qb + dq);
    float4 ov;
    ov.x = acc.x + c0*we0.x + c1*we1.x + c2*we2.x;
    ov.y = acc.y + c0*we0.y + c1*we1.y + c2*we2.y;
    ov.z = acc.z + c0*we0.z + c1*we1.z + c2*we2.z;
    ov.w = acc.w + c0*we0.w + c1*we1.w + c2*we2.w;
    *(float4*)(aog + (i0+w)*INNER + qb + dq) = ov;
  }
}

// ---- fused per-row layer tail: Wo+gate1+LN2+FFN+gate2 (+next QKV | energy) ----
__global__ __launch_bounds__(512) void k_layer(
    float* nodes, const float* __restrict__ aog,
    float* qg_n, float* kT_n, float* vg_n,
    const f16* __restrict__ Woh, const float* __restrict__ bo,
    const float* __restrict__ Wg1,
    const float* __restrict__ ln2_g, const float* __restrict__ ln2_b,
    const f16* __restrict__ W1h, const float* __restrict__ b1,
    const f16* __restrict__ W2h, const float* __restrict__ b2,
    const float* __restrict__ Wg2,
    const float* __restrict__ ln1_g_n, const float* __restrict__ ln1_b_n,
    const f16* __restrict__ Wqh_n, const float* __restrict__ bq_n,
    const float* __restrict__ Wkv_n, const float* __restrict__ bkv_n,
    const float* __restrict__ be_n,
    const float* __restrict__ out_w, const float* __restrict__ out_b,
    float* eout, int has_next)
{
  __shared__ __align__(16) float SC[6144];   // matvec partials
  __shared__ __align__(16) float qs[INNER];  // FFN hidden
  __shared__ __align__(16) float aos[INNER]; // attention output row
  __shared__ __align__(16) float xsm[DIM];
  const int t = threadIdx.x, i = blockIdx.x;
  const int w = t>>6, l = t&63;

  aos[t] = aog[i*INNER + t];
  float nd0 = nodes[i*DIM + l];        // per-wave redundant row state
  float nd1 = nodes[i*DIM + 64 + l];
  __syncthreads();                               // B1

  // ---- Wo (fp16) + gate1 + LN2 ----
  mvp512_128h(aos, Woh, SC, t);
  __syncthreads();                               // B2
  {
    float o0 = bo[l], o1 = bo[64+l];
#pragma unroll
    for(int fg=0; fg<32; fg++){ o0 += SC[fg*DIM + l]; o1 += SC[fg*DIM + 64 + l]; }
    gate_wave(o0, o1, nd0, nd1, Wg1, l);
    float x0, x1;
    ln_wave(nd0, nd1, ln2_g, ln2_b, l, x0, x1);
    xsm[l] = x0; xsm[64+l] = x1;
  }
  __syncthreads();                               // B3 (xsm ready; SC free)

  // ---- FFN (fp16) ----
  mvp128_512h(xsm, W1h, SC, t);
  __syncthreads();                               // B4
  {
    float a = b1[t];
#pragma unroll
    for(int fg=0; fg<8; fg++) a += SC[fg*INNER + t];
    qs[t] = 0.5f*a*(1.f + erff(a*0.70710678118654752440f));
  }
  __syncthreads();                               // B5 (hidden ready; SC free)
  mvp512_128h(qs, W2h, SC, t);
  __syncthreads();                               // B6
  {
    float y0 = b2[l], y1 = b2[64+l];
#pragma unroll
    for(int fg=0; fg<32; fg++){ y0 += SC[fg*DIM + l]; y1 += SC[fg*DIM + 64 + l]; }
    gate_wave(y0, y1, nd0, nd1, Wg2, l);
    if(w==0){ nodes[i*DIM + l] = nd0; nodes[i*DIM + 64 + l] = nd1; }
    if(has_next){
      float x0, x1;
      ln_wave(nd0, nd1, ln1_g_n, ln1_b_n, l, x0, x1);
      xsm[l] = x0; xsm[64+l] = x1;
    } else if(w==0){
      float ev = nd0*out_w[l] + nd1*out_w[64+l];
      ev = wred_sum(ev);
      if(l==0) eout[i] = ev + out_b[0];
    }
  }
  if(has_next){
    __syncthreads();                             // B7 (xsm ready; SC free)
    qkv_tail(xsm, i, Wqh_n, bq_n, Wkv_n, bkv_n, be_n,
             qg_n, kT_n, vg_n, SC, t);           // B8
  }
}

extern "C" void kernel_launch(void* const* d_in, const int* in_sizes, int n_in,
                              void* d_out, int out_size, void* d_ws, size_t ws_size,
                              hipStream_t stream){
  const float* coords   = (const float*)d_in[0];
  const int*   bonds    = (const int*  )d_in[1];
  const float* noise    = (const float*)d_in[2];
  const float* atom_emb = (const float*)d_in[3];
  const float* ln1_g = (const float*)d_in[4];
  const float* ln1_b = (const float*)d_in[5];
  const float* Wq    = (const float*)d_in[6];
  const float* bq    = (const float*)d_in[7];
  const float* Wkv   = (const float*)d_in[8];
  const float* bkv   = (const float*)d_in[9];
  const float* We    = (const float*)d_in[10];
  const float* be    = (const float*)d_in[11];
  const float* Wo    = (const float*)d_in[12];
  const float* bo    = (const float*)d_in[13];
  const float* Wg1   = (const float*)d_in[14];
  const float* ln2_g = (const float*)d_in[15];
  const float* ln2_b = (const float*)d_in[16];
  const float* W1    = (const float*)d_in[17];
  const float* b1    = (const float*)d_in[18];
  const float* W2    = (const float*)d_in[19];
  const float* b2    = (const float*)d_in[20];
  const float* Wg2   = (const float*)d_in[21];
  const float* out_w = (const float*)d_in[22];
  const float* out_b = (const float*)d_in[23];

  // workspace carve (bytes); total ~7.4 MB
  char* base = (char*)d_ws;
  float* nodes = (float*)(base);                    // 131072 B
  float* qb0   = (float*)(base + 131072);           // 524288 B
  float* qb1   = (float*)(base + 655360);           // 524288 B
  float* aog   = (float*)(base + 1179648);          // 524288 B
  float* ebg   = (float*)(base + 1703936);          // 786432 B
  float* kb0   = (float*)(base + 2490368);          // 524288 B
  float* kb1   = (float*)(base + 3014656);
  float* vb0   = (float*)(base + 3538944);
  float* vb1   = (float*)(base + 4063232);
  f16*   Wqh   = (f16*  )(base + 4587520);          // 786432 B
  f16*   Woh   = (f16*  )(base + 5373952);          // 786432 B
  f16*   W1h   = (f16*  )(base + 6160384);          // 786432 B
  f16*   W2h   = (f16*  )(base + 6946816);          // 786432 B
  float* eout  = (float*)d_out;

  k_prep<<<512, 512, 0, stream>>>(Wq, Wo, W1, W2, Wqh, Woh, W1h, W2h);
  k_qkv0<<<NN+32, 512, 0, stream>>>(atom_emb, noise, nodes, ln1_g, ln1_b,
                                    Wqh, bq, Wkv, bkv, be,
                                    qb0, kb0, vb0,
                                    bonds, coords, ebg);
  for(int l=0; l<DEPTH; l++){
    int has_next = (l < DEPTH-1);
    int ln = has_next ? l+1 : l;    // keep pointers valid when unused
    float* qcur = (l&1)? qb1:qb0;  float* kcur = (l&1)? kb1:kb0;  float* vcur = (l&1)? vb1:vb0;
    float* qnxt = (l&1)? qb0:qb1;  float* knxt = (l&1)? kb0:kb1;  float* vnxt = (l&1)? vb0:vb1;
    const f16* Woh_l  = Woh + (size_t)l*INNER*DIM;
    const f16* W1h_l  = W1h + (size_t)l*DIM*4*DIM;
    const f16* W2h_l  = W2h + (size_t)l*4*DIM*DIM;
    const f16* Wqh_n  = Wqh + (size_t)ln*DIM*INNER;
    const float* Wkv_n = Wkv + (size_t)ln*DIM*2*INNER;
    k_attn<<<NN, 512, 0, stream>>>(
      qcur, kcur, vcur, ebg,
      We + (size_t)l*3*INNER, aog,
      Woh_l, W1h_l, W2h_l, Wqh_n, Wkv_n, has_next);
    k_layer<<<NN, 512, 0, stream>>>(
      nodes, aog,
      qnxt, knxt, vnxt,
      Woh_l, bo + (size_t)l*DIM, Wg1 + (size_t)l*3*DIM,
      ln2_g + (size_t)l*DIM, ln2_b + (size_t)l*DIM,
      W1h_l, b1 + (size_t)l*4*DIM,
      W2h_l, b2 + (size_t)l*DIM, Wg2 + (size_t)l*3*DIM,
      ln1_g + (size_t)ln*DIM, ln1_b + (size_t)ln*DIM,
      Wqh_n, bq + (size_t)ln*INNER,
      Wkv_n, bkv + (size_t)ln*2*INNER,
      be  + (size_t)ln*INNER,
      out_w, out_b, eout, has_next);
  }
}